// Round 1
// baseline (652.401 us; speedup 1.0000x reference)
//
#include <hip/hip_runtime.h>

// RROIMask: per-box affine crop (bilinear, zero border) of feature maps.
// fm:    [S=2, B=8, C=32, H=128, W=128] f32
// boxes: [S=2, B=8, M=16, 4] f32  (x1,y1,x3,y3)
// out:   [S=2, B*M=128, C=32, 128, 128] f32
//
// Output = 512 MB  -> HBM-write-bound. Input = 16 MB (L2/L3 resident).
// One thread produces 4 consecutive u-pixels (float4 store).

#define SS 2
#define BB 8
#define MM 16
#define CC 32
#define HH 128
#define WW 128
#define OUT_W 128
#define OUT_H 128

__global__ __launch_bounds__(256) void rroi_kernel(
    const float* __restrict__ fm,
    const float* __restrict__ boxes,
    float* __restrict__ out)
{
    unsigned t = blockIdx.x * 256u + threadIdx.x;   // [0, 2^25)
    // decompose: t = (((((s*128)+bm)*32+c)*128+v)*32+ug)
    unsigned ug = t & 31u;            // group of 4 u-pixels
    unsigned v  = (t >> 5) & 127u;
    unsigned c  = (t >> 12) & 31u;
    unsigned bm = (t >> 17) & 127u;
    unsigned s  = t >> 24;

    unsigned b = bm >> 4, m = bm & 15u;
    const float* bx = boxes + ((((s * BB + b) * MM + m) << 2));
    float x1 = bx[0], y1 = bx[1], x3 = bx[2], y3 = bx[3];

    // y interpolation (shared across the 4 u-pixels)
    float sy  = y1 + (float)v * ((y3 - y1) * (1.0f / OUT_H)); // /128 exact
    float y0f = floorf(sy);
    float wy  = sy - y0f;
    int   y0  = (int)y0f;
    int   yA  = y0 + 1;
    float my0 = (y0 >= 0 && y0 < HH) ? 1.0f : 0.0f;
    float my1 = (yA >= 0 && yA < HH) ? 1.0f : 0.0f;
    int   y0c = min(max(y0, 0), HH - 1);
    int   yAc = min(max(yA, 0), HH - 1);
    float wy0 = (1.0f - wy) * my0;
    float wy1 = wy * my1;

    const float* plane = fm + ((size_t)((s * BB + b) * CC + c)) * (HH * WW);
    const float* row0  = plane + y0c * WW;
    const float* row1  = plane + yAc * WW;

    float dx = (x3 - x1) * (1.0f / OUT_W);   // /128 exact in fp32
    float u0 = (float)(ug << 2);

    float4 res;
    float* rp = reinterpret_cast<float*>(&res);
    #pragma unroll
    for (int i = 0; i < 4; ++i) {
        float sx  = x1 + (u0 + (float)i) * dx;
        float x0f = floorf(sx);
        float wx  = sx - x0f;
        int   x0  = (int)x0f;
        int   xA  = x0 + 1;
        float mx0 = (x0 >= 0 && x0 < WW) ? 1.0f : 0.0f;
        float mx1 = (xA >= 0 && xA < WW) ? 1.0f : 0.0f;
        int   x0c = min(max(x0, 0), WW - 1);
        int   xAc = min(max(xA, 0), WW - 1);
        float wx0 = (1.0f - wx) * mx0;
        float wx1 = wx * mx1;

        float f00 = row0[x0c], f01 = row0[xAc];
        float f10 = row1[x0c], f11 = row1[xAc];
        float fx0 = f00 * wx0 + f01 * wx1;
        float fx1 = f10 * wx0 + f11 * wx1;
        rp[i] = fx0 * wy0 + fx1 * wy1;
    }

    *reinterpret_cast<float4*>(out + ((size_t)t << 2)) = res;
}

extern "C" void kernel_launch(void* const* d_in, const int* in_sizes, int n_in,
                              void* d_out, int out_size, void* d_ws, size_t ws_size,
                              hipStream_t stream) {
    const float* fm    = (const float*)d_in[0];
    const float* boxes = (const float*)d_in[1];
    float* out         = (float*)d_out;

    const unsigned total_threads = 1u << 25;   // out_size / 4
    dim3 block(256);
    dim3 grid(total_threads / 256);
    rroi_kernel<<<grid, block, 0, stream>>>(fm, boxes, out);
}